// Round 9
// baseline (305.104 us; speedup 1.0000x reference)
//
#include <hip/hip_runtime.h>
#include <hip/hip_bf16.h>

typedef __bf16 bf16;
typedef __bf16 bf16x8 __attribute__((ext_vector_type(8)));
typedef float floatx4 __attribute__((ext_vector_type(4)));

#define MFMA16(a, b, c) __builtin_amdgcn_mfma_f32_16x16x32_bf16((a), (b), (c), 0, 0, 0)

__device__ inline void gload_lds16(const void* g, void* l) {
    __builtin_amdgcn_global_load_lds((__attribute__((address_space(1))) void*)g,
                                     (__attribute__((address_space(3))) void*)l, 16, 0, 0);
}

// ---------------------------------------------------------------------------
// Kernel 1 (fused prep): three roles by blockIdx.x
//   [0,2048)     fold_w2:  W2fT[i*64+l, p] = sum_j W2[p,i*64+j] W[l,j]  (bf16)
//   [2048,2112)  b2f:      b2f[i*64+l]     = sum_j b2[i*64+j]   W[l,j]
//   [2112,3136)  mlp1:     h = silu(Y @ W1 + b1)  via MFMA (K=64), bf16 out
// R9: LDS 45056 -> 36864 (fold_w2's sT aliases sW/sA across a barrier;
// sW/sA dead after the MFMA loop) -> 3 -> 4 blocks/CU.
// ---------------------------------------------------------------------------
__global__ __launch_bounds__(256) void prep_fused(
    const float* __restrict__ W2,  // [4096,4096]
    const float* __restrict__ W,   // [64,64]
    const float* __restrict__ b2,  // [4096]
    const float* __restrict__ Y,   // [4096,64]
    const float* __restrict__ W1,  // [64,4096]
    const float* __restrict__ b1,  // [4096]
    bf16* __restrict__ W2fT,       // [4096,4096] (n, p)
    float* __restrict__ b2f,       // [4096]
    bf16* __restrict__ h)          // [4096,4096]
{
    __shared__ __align__(16) char smem[36864];
    int t = threadIdx.x, bid = blockIdx.x;
    int w = t >> 6, l = t & 63;
    int lm = l & 15, q2 = l >> 4, q8 = q2 * 8;

    if (bid < 2048) {
        // ---- fold_w2 ----
        int pt = bid & 31, i = bid >> 5;
        bf16* sW = (bf16*)smem;          // 64*72  = 9216 B   [0, 9216)
        bf16* sA = sW + 64 * 72;         // 128*72 = 18432 B  [9216, 27648)
        bf16* sT = (bf16*)smem;          // 64*136 = 17408 B  ALIASES sW/sA
        int p0 = pt * 128;

        // W staging: vectorized (4 float4/thread, packed uint2 LDS writes)
#pragma unroll
        for (int kk = 0; kk < 4; kk++) {
            int idx4 = t + 256 * kk;           // 1024 float4 total
            float4 v = *(const float4*)(W + (size_t)idx4 * 4);
            int row = (idx4 * 4) >> 6, col = (idx4 * 4) & 63;
            bf16 tmp[4] = {(bf16)v.x, (bf16)v.y, (bf16)v.z, (bf16)v.w};
            *(uint2*)(sW + row * 72 + col) = *(const uint2*)tmp;
        }
        {
            const float* src = W2 + (size_t)p0 * 4096 + i * 64;
#pragma unroll
            for (int kk = 0; kk < 8; kk++) {
                int c = t + 256 * kk;
                int row = c >> 4, j4 = (c & 15) * 4;
                float4 v = *(const float4*)(src + (size_t)row * 4096 + j4);
                bf16 tmp[4] = {(bf16)v.x, (bf16)v.y, (bf16)v.z, (bf16)v.w};
                *(uint2*)(sA + row * 72 + j4) = *(const uint2*)tmp;
            }
        }
        __syncthreads();

        floatx4 acc[2][4] = {};
#pragma unroll
        for (int kc = 0; kc < 2; kc++) {
            bf16x8 a0 = *(const bf16x8*)(sA + (w * 32 + lm) * 72 + kc * 32 + q8);
            bf16x8 a1 = *(const bf16x8*)(sA + (w * 32 + 16 + lm) * 72 + kc * 32 + q8);
#pragma unroll
            for (int jn = 0; jn < 4; jn++) {
                bf16x8 bf_ = *(const bf16x8*)(sW + (jn * 16 + lm) * 72 + kc * 32 + q8);
                acc[0][jn] = MFMA16(a0, bf_, acc[0][jn]);
                acc[1][jn] = MFMA16(a1, bf_, acc[1][jn]);
            }
        }
        __syncthreads();   // all waves' sW/sA reads retired -> sT may overwrite
#pragma unroll
        for (int im = 0; im < 2; im++)
#pragma unroll
            for (int jn = 0; jn < 4; jn++) {
                int pr = w * 32 + im * 16 + q2 * 4;
                int lc = jn * 16 + lm;
                union { bf16 h4[4]; uint2 u; } pk;
#pragma unroll
                for (int r = 0; r < 4; r++) pk.h4[r] = (bf16)acc[im][jn][r];
                *(uint2*)(sT + lc * 136 + pr) = pk.u;
            }
        __syncthreads();
#pragma unroll
        for (int kk = 0; kk < 4; kk++) {
            int c = t + 256 * kk;
            int row = c >> 4, off = (c & 15) * 8;
            uint4 v = *(const uint4*)(sT + row * 136 + off);
            *(uint4*)(W2fT + (size_t)(i * 64 + row) * 4096 + p0 + off) = v;
        }
        return;
    }

    if (bid < 2112) {
        // ---- b2f ----
        int i = bid - 2048;
        if (t < 64) {
            float acc = 0.f;
            const float* b2r = b2 + i * 64;
            const float* wr_ = W + t * 64;
#pragma unroll
            for (int j = 0; j < 64; j++) acc = fmaf(b2r[j], wr_[j], acc);
            b2f[i * 64 + t] = acc;
        }
        return;
    }

    // ---- mlp1 via MFMA: h[m,n] = silu(sum_k Y[m,k] W1[k,n] + b1[n]) ----
    {
        int q = bid - 2112;
        int m0 = (q >> 5) * 128, n0 = (q & 31) * 128;
        bf16* sY = (bf16*)smem;          // 128*72  (Y[m,k])   18432 B
        bf16* sWT = sY + 128 * 72;       // 128*72  (W1T[n,k]) 18432 B

#pragma unroll
        for (int kk = 0; kk < 8; kk++) {
            int c = t + 256 * kk;
            int row = c >> 4, c4 = (c & 15) * 4;
            float4 v = *(const float4*)(Y + (size_t)(m0 + row) * 64 + c4);
            bf16 tmp[4] = {(bf16)v.x, (bf16)v.y, (bf16)v.z, (bf16)v.w};
            *(uint2*)(sY + row * 72 + c4) = *(const uint2*)tmp;
        }
#pragma unroll
        for (int kk = 0; kk < 8; kk++) {
            int c = t + 256 * kk;
            int k = c >> 5, j4 = (c & 31) * 4;
            float4 v = *(const float4*)(W1 + (size_t)k * 4096 + n0 + j4);
            sWT[(j4 + 0) * 72 + k] = (bf16)v.x;
            sWT[(j4 + 1) * 72 + k] = (bf16)v.y;
            sWT[(j4 + 2) * 72 + k] = (bf16)v.z;
            sWT[(j4 + 3) * 72 + k] = (bf16)v.w;
        }
        __syncthreads();

        int wn = (w & 1) * 64, wm = (w >> 1) * 64;
        floatx4 acc[4][4] = {};
#pragma unroll
        for (int kc = 0; kc < 2; kc++) {
            bf16x8 af[4], bfr[4];
#pragma unroll
            for (int i = 0; i < 4; i++)
                af[i] = *(const bf16x8*)(sWT + (wn + i * 16 + lm) * 72 + kc * 32 + q8);
#pragma unroll
            for (int j = 0; j < 4; j++)
                bfr[j] = *(const bf16x8*)(sY + (wm + j * 16 + lm) * 72 + kc * 32 + q8);
#pragma unroll
            for (int i = 0; i < 4; i++)
#pragma unroll
                for (int j = 0; j < 4; j++)
                    acc[i][j] = MFMA16(af[i], bfr[j], acc[i][j]);
        }
#pragma unroll
        for (int i = 0; i < 4; i++) {
            int nb = n0 + wn + i * 16 + q2 * 4;
            float4 bv = *(const float4*)(b1 + nb);
            float bb[4] = {bv.x, bv.y, bv.z, bv.w};
#pragma unroll
            for (int j = 0; j < 4; j++) {
                int m = m0 + wm + j * 16 + lm;
                union { bf16 h4[4]; uint2 u; } pk;
#pragma unroll
                for (int r = 0; r < 4; r++) {
                    float v = acc[i][j][r] + bb[r];
                    v = v / (1.f + __expf(-v));
                    pk.h4[r] = (bf16)v;
                }
                *(uint2*)(h + (size_t)m * 4096 + nb) = pk.u;
            }
        }
    }
}

// ---------------------------------------------------------------------------
// Kernel 2 (R8, frozen): C = A @ BT^T + bias.  256x256 tile, 512 thr
// (8 waves 2Mx4N, 128x64 C/wave), BK=64 2-slot double-buffer, ONE barrier
// per 64 K-cols, counted lgkm gates, XCD 4x8 remap.  116.5us measured.
// ---------------------------------------------------------------------------
__global__ __launch_bounds__(512, 2) void gemm_bt_bias(
    const bf16* __restrict__ A, const bf16* __restrict__ BT,
    const float* __restrict__ bias, bf16* __restrict__ C,
    int M, int N, int K)
{
    __shared__ __align__(16) char lds[131072];  // 2 slots x (A 32K | B 32K)

    int t = threadIdx.x, w = t >> 6, l = t & 63;
    int lm = l & 15, q2 = l >> 4;
    int wm = w >> 2, wn = w & 3;

    int bid = blockIdx.x;
    int xcd = bid & 7, local = bid >> 3;
    int m0 = ((xcd & 3) * 4 + (local >> 3)) * 256;
    int n0 = ((xcd >> 2) * 8 + (local & 7)) * 256;

    // staging: 4 x 16B chunks per thread per operand per stage (2048 chunks).
    // chunk ch: row = ch>>3, phys pos = ch&7, holds source k-chunk
    // (ch&7) ^ (row&7)  [involutive].
    const bf16 *gA0, *gA1, *gA2, *gA3, *gB0, *gB1, *gB2, *gB3;
    {
        int ch, row, ko;
        ch = t;        row = ch >> 3; ko = ((ch & 7) ^ (row & 7)) * 8;
        gA0 = A + (size_t)(m0 + row) * K + ko; gB0 = BT + (size_t)(n0 + row) * K + ko;
        ch = t + 512;  row = ch >> 3; ko = ((ch & 7) ^ (row & 7)) * 8;
        gA1 = A + (size_t)(m0 + row) * K + ko; gB1 = BT + (size_t)(n0 + row) * K + ko;
        ch = t + 1024; row = ch >> 3; ko = ((ch & 7) ^ (row & 7)) * 8;
        gA2 = A + (size_t)(m0 + row) * K + ko; gB2 = BT + (size_t)(n0 + row) * K + ko;
        ch = t + 1536; row = ch >> 3; ko = ((ch & 7) ^ (row & 7)) * 8;
        gA3 = A + (size_t)(m0 + row) * K + ko; gB3 = BT + (size_t)(n0 + row) * K + ko;
    }
    const int dstb = t * 16;   // lane-consecutive within wave (t = w*64 + l)

    auto issue = [&](int slot) {
        char* slab = lds + (slot << 16);
        gload_lds16(gA0, slab + dstb);
        gload_lds16(gA1, slab + 8192 + dstb);
        gload_lds16(gA2, slab + 16384 + dstb);
        gload_lds16(gA3, slab + 24576 + dstb);
        gload_lds16(gB0, slab + 32768 + dstb);
        gload_lds16(gB1, slab + 40960 + dstb);
        gload_lds16(gB2, slab + 49152 + dstb);
        gload_lds16(gB3, slab + 57344 + dstb);
        gA0 += 64; gA1 += 64; gA2 += 64; gA3 += 64;
        gB0 += 64; gB1 += 64; gB2 += 64; gB3 += 64;
    };

    // fragment read bases: row*128 + ((q2)^(lm&7))*16; kc=1 flips bit 6 (^64)
    const int swz = (q2 ^ (lm & 7)) * 16;
    const int base_a = (wm * 128 + lm) * 128 + swz;
    const int base_b = 32768 + (wn * 64 + lm) * 128 + swz;

    floatx4 acc[8][4] = {};

    auto body = [&](int kt, bool doIssue) {
        const char* slab = lds + ((kt & 1) << 16);
        bf16x8 bv[4], a0[4], a1[4];
        // ================= K-half 0 =================
#pragma unroll
        for (int j = 0; j < 4; j++) bv[j] = *(const bf16x8*)(slab + base_b + j * 2048);
#pragma unroll
        for (int i = 0; i < 4; i++) a0[i] = *(const bf16x8*)(slab + base_a + i * 2048);
        __builtin_amdgcn_sched_barrier(0);   // pin: bv,a0 issue before a1
#pragma unroll
        for (int i = 0; i < 4; i++) a1[i] = *(const bf16x8*)(slab + base_a + (4 + i) * 2048);
        if (doIssue) issue((kt + 1) & 1);    // stage next tile (8 gloads, vmcnt)
        asm volatile("s_waitcnt lgkmcnt(4)" ::: "memory");
        __builtin_amdgcn_sched_barrier(0);
        __builtin_amdgcn_s_setprio(1);
#pragma unroll
        for (int i = 0; i < 4; i++)
#pragma unroll
            for (int j = 0; j < 4; j++) acc[i][j] = MFMA16(bv[j], a0[i], acc[i][j]);
        __builtin_amdgcn_s_setprio(0);
        asm volatile("s_waitcnt lgkmcnt(0)" ::: "memory");
        __builtin_amdgcn_sched_barrier(0);
        __builtin_amdgcn_s_setprio(1);
#pragma unroll
        for (int i = 0; i < 4; i++)
#pragma unroll
            for (int j = 0; j < 4; j++) acc[4 + i][j] = MFMA16(bv[j], a1[i], acc[4 + i][j]);
        __builtin_amdgcn_s_setprio(0);
        __builtin_amdgcn_sched_barrier(0);
        // ================= K-half 1 (^64 on swizzled chunk) =================
#pragma unroll
        for (int j = 0; j < 4; j++) bv[j] = *(const bf16x8*)(slab + (base_b ^ 64) + j * 2048);
#pragma unroll
        for (int i = 0; i < 4; i++) a0[i] = *(const bf16x8*)(slab + (base_a ^ 64) + i * 2048);
        __builtin_amdgcn_sched_barrier(0);
#pragma unroll
        for (int i = 0; i < 4; i++) a1[i] = *(const bf16x8*)(slab + (base_a ^ 64) + (4 + i) * 2048);
        asm volatile("s_waitcnt lgkmcnt(4)" ::: "memory");
        __builtin_amdgcn_sched_barrier(0);
        __builtin_amdgcn_s_setprio(1);
#pragma unroll
        for (int i = 0; i < 4; i++)
#pragma unroll
            for (int j = 0; j < 4; j++) acc[i][j] = MFMA16(bv[j], a0[i], acc[i][j]);
        __builtin_amdgcn_s_setprio(0);
        asm volatile("s_waitcnt lgkmcnt(0)" ::: "memory");
        __builtin_amdgcn_sched_barrier(0);
        __builtin_amdgcn_s_setprio(1);
#pragma unroll
        for (int i = 0; i < 4; i++)
#pragma unroll
            for (int j = 0; j < 4; j++) acc[4 + i][j] = MFMA16(bv[j], a1[i], acc[4 + i][j]);
        __builtin_amdgcn_s_setprio(0);
        __builtin_amdgcn_sched_barrier(0);
        // ================= bottom sync =================
        if (doIssue) {
            asm volatile("s_waitcnt vmcnt(0)" ::: "memory");  // stage kt+1 landed
            __builtin_amdgcn_s_barrier();                     // ... and visible
            __builtin_amdgcn_sched_barrier(0);
        }
    };

    issue(0);                                       // prime slot 0
    asm volatile("s_waitcnt vmcnt(0)" ::: "memory");
    __builtin_amdgcn_s_barrier();
    __builtin_amdgcn_sched_barrier(0);
    const int KT = K >> 6;                          // 64 iters of BK=64
    for (int kt = 0; kt < KT; ++kt) body(kt, kt + 1 < KT);

    // epilogue: bias + packed uint2 stores (acc holds 4 consecutive n @ fixed m)
#pragma unroll
    for (int i = 0; i < 8; i++) {
        int m = m0 + wm * 128 + i * 16 + lm;
#pragma unroll
        for (int j = 0; j < 4; j++) {
            int nb = n0 + wn * 64 + j * 16 + q2 * 4;
            float4 b4 = *(const float4*)(bias + nb);
            float bb[4] = {b4.x, b4.y, b4.z, b4.w};
            union { bf16 h4[4]; uint2 u; } pk;
#pragma unroll
            for (int r = 0; r < 4; r++) pk.h4[r] = (bf16)(acc[i][j][r] + bb[r]);
            *(uint2*)(C + (size_t)m * N + nb) = pk.u;
        }
    }
}

// ---------------------------------------------------------------------------
// Kernel 3: out = F X F^T (X symmetric).
// R9: sT aliases sX (x-data dead after S2's mm; extra barrier between the
// mm reads and sT writes, and between S3's mm reads and the store-stage) ->
// LDS 27648 -> 18432 B -> 5 -> 8 blocks/CU.
// ---------------------------------------------------------------------------
#define ST 72
__global__ __launch_bounds__(256) void batched_congruence(
    const float* __restrict__ x,   // [B,48,48]
    const bf16* __restrict__ F,    // [B,4096]
    float* __restrict__ out)       // [B,4096]
{
    __shared__ __align__(16) bf16 sXT[64 * ST];   // sX, then sT, then stage
    __shared__ __align__(16) bf16 sF[64 * ST];
    bf16* sX = sXT;
    bf16* sT = sXT;
    int t = threadIdx.x, w = t >> 6, l = t & 63;
    int b = blockIdx.x;
    int lm = l & 15, q2 = l >> 4, q8 = q2 * 8;
    int r0 = (w >> 1) * 32, c0 = (w & 1) * 32;

    const float4* xb = (const float4*)(x + (size_t)b * 2304);
    float4 v0 = xb[t];
    float4 v1 = xb[t + 256];
    float4 v2 = (t < 64) ? xb[t + 512] : make_float4(0.f, 0.f, 0.f, 0.f);

    {
        const uint4* gf = (const uint4*)(F + (size_t)b * 4096);
#pragma unroll
        for (int kk = 0; kk < 2; kk++) {
            int c = t + 256 * kk;
            *(uint4*)(sF + (c >> 3) * ST + (c & 7) * 8) = gf[c];
        }
    }
    // zero X border + padded-diagonal ones (disjoint from x-fill)
    {
        unsigned* sx32 = (unsigned*)sX;
#pragma unroll
        for (int kk = 0; kk < 4; kk++) {
            int idx = t + 256 * kk;
            if (idx < 384) {
                int r = idx >> 3, d = 24 + (idx & 7);
                sx32[r * 36 + d] = 0u;
            } else if (idx < 896) {
                int k2 = idx - 384;
                int r = 48 + (k2 >> 5), d = k2 & 31;
                unsigned val = 0u;
                if (d == (r >> 1)) val = (r & 1) ? 0x3F800000u : 0x00003F80u;
                sx32[r * 36 + d] = val;
            }
        }
    }
    // x fill: rows 0-47, cols 0-47
    {
        int c = t;
        bf16 p4[4];
        p4[0] = (bf16)v0.x; p4[1] = (bf16)v0.y; p4[2] = (bf16)v0.z; p4[3] = (bf16)v0.w;
        *(uint2*)(sX + (c / 12) * ST + (c % 12) * 4) = *(const uint2*)p4;
        c = t + 256;
        p4[0] = (bf16)v1.x; p4[1] = (bf16)v1.y; p4[2] = (bf16)v1.z; p4[3] = (bf16)v1.w;
        *(uint2*)(sX + (c / 12) * ST + (c % 12) * 4) = *(const uint2*)p4;
        if (t < 64) {
            c = t + 512;
            p4[0] = (bf16)v2.x; p4[1] = (bf16)v2.y; p4[2] = (bf16)v2.z; p4[3] = (bf16)v2.w;
            *(uint2*)(sX + (c / 12) * ST + (c % 12) * 4) = *(const uint2*)p4;
        }
    }
    __syncthreads();

    auto mm = [&](const bf16* PA, const bf16* PB, floatx4 acc[2][2]) {
#pragma unroll
        for (int kc = 0; kc < 2; kc++) {
            bf16x8 a0 = *(const bf16x8*)(PA + (r0 + lm) * ST + kc * 32 + q8);
            bf16x8 a1 = *(const bf16x8*)(PA + (r0 + 16 + lm) * ST + kc * 32 + q8);
            bf16x8 b0 = *(const bf16x8*)(PB + (c0 + lm) * ST + kc * 32 + q8);
            bf16x8 b1 = *(const bf16x8*)(PB + (c0 + 16 + lm) * ST + kc * 32 + q8);
            acc[0][0] = MFMA16(a0, b0, acc[0][0]);
            acc[0][1] = MFMA16(a0, b1, acc[0][1]);
            acc[1][0] = MFMA16(a1, b0, acc[1][0]);
            acc[1][1] = MFMA16(a1, b1, acc[1][1]);
        }
    };

    floatx4 z = {0.f, 0.f, 0.f, 0.f};
    {   // S2: Q = X . F^T; transposed store -> sT = T row-major (sT aliases sX)
        floatx4 acc[2][2] = {{z, z}, {z, z}};
        mm(sX, sF, acc);
        __syncthreads();   // all waves' sX reads retired -> safe to overwrite
#pragma unroll
        for (int i = 0; i < 2; i++)
#pragma unroll
            for (int j = 0; j < 2; j++) {
                int R = r0 + i * 16 + q2 * 4;
                int Cc = c0 + j * 16 + lm;
                union { bf16 h4[4]; uint2 u; } pk;
#pragma unroll
                for (int r = 0; r < 4; r++) pk.h4[r] = (bf16)acc[i][j][r];
                *(uint2*)(sT + Cc * ST + R) = pk.u;
            }
    }
    __syncthreads();
    {   // S3: out = T . F^T; coalesced store via stage-reuse (fp32, 2 halves)
        floatx4 acc[2][2] = {{z, z}, {z, z}};
        mm(sT, sF, acc);
        __syncthreads();   // all waves' sT reads retired -> stage may overwrite
        float* stage = (float*)sXT;           // 32 x 64 fp32 = 8 KB
        float* ob = out + (size_t)b * 4096;
        // half 0: rows 0..31 come from waves 0,1 (r0 == 0)
        if (w < 2) {
#pragma unroll
            for (int i = 0; i < 2; i++)
#pragma unroll
                for (int j = 0; j < 2; j++) {
                    int R = r0 + i * 16 + q2 * 4;
                    int Cc = c0 + j * 16 + lm;
#pragma unroll
                    for (int r = 0; r < 4; r++) stage[(R + r) * 64 + Cc] = acc[i][j][r];
                }
        }
        __syncthreads();
#pragma unroll
        for (int kk = 0; kk < 2; kk++) {
            int idx = t + 256 * kk;           // 512 float4 = 2048 floats
            *(float4*)(ob + (size_t)idx * 4) = *(const float4*)(stage + (size_t)idx * 4);
        }
        __syncthreads();
        // half 1: rows 32..63 from waves 2,3 (r0 == 32)
        if (w >= 2) {
#pragma unroll
            for (int i = 0; i < 2; i++)
#pragma unroll
                for (int j = 0; j < 2; j++) {
                    int R = r0 + i * 16 + q2 * 4 - 32;
                    int Cc = c0 + j * 16 + lm;
#pragma unroll
                    for (int r = 0; r < 4; r++) stage[(R + r) * 64 + Cc] = acc[i][j][r];
                }
        }
        __syncthreads();
#pragma unroll
        for (int kk = 0; kk < 2; kk++) {
            int idx = t + 256 * kk;
            *(float4*)(ob + 2048 + (size_t)idx * 4) = *(const float4*)(stage + (size_t)idx * 4);
        }
    }
}

// ---------------------------------------------------------------------------
extern "C" void kernel_launch(void* const* d_in, const int* in_sizes, int n_in,
                              void* d_out, int out_size, void* d_ws, size_t ws_size,
                              hipStream_t stream) {
    const float* x  = (const float*)d_in[0];
    const float* Y  = (const float*)d_in[2];
    const float* W  = (const float*)d_in[3];
    const float* W1 = (const float*)d_in[4];
    const float* b1 = (const float*)d_in[5];
    const float* W2 = (const float*)d_in[6];
    const float* b2 = (const float*)d_in[7];
    float* out = (float*)d_out;

    const size_t NN = (size_t)4096 * 4096;
    bf16* h    = (bf16*)d_ws;
    bf16* W2fT = h + NN;
    bf16* emb  = W2fT + NN;
    float* b2f = (float*)d_out;  // stashed in d_out; consumed by GEMM, then overwritten

    prep_fused<<<3136, 256, 0, stream>>>(W2, W, b2, Y, W1, b1, W2fT, b2f, h);
    gemm_bt_bias<<<256, 512, 0, stream>>>(h, W2fT, b2f, emb, 4096, 4096, 4096);
    batched_congruence<<<4096, 256, 0, stream>>>(x, emb, out);
}

// Round 10
// 293.967 us; speedup vs baseline: 1.0379x; 1.0379x over previous
//
#include <hip/hip_runtime.h>
#include <hip/hip_bf16.h>

typedef __bf16 bf16;
typedef __bf16 bf16x8 __attribute__((ext_vector_type(8)));
typedef float floatx4 __attribute__((ext_vector_type(4)));

#define MFMA16(a, b, c) __builtin_amdgcn_mfma_f32_16x16x32_bf16((a), (b), (c), 0, 0, 0)

__device__ inline void gload_lds16(const void* g, void* l) {
    __builtin_amdgcn_global_load_lds((__attribute__((address_space(1))) void*)g,
                                     (__attribute__((address_space(3))) void*)l, 16, 0, 0);
}

// ---------------------------------------------------------------------------
// Kernel 1 (fused prep): three roles by blockIdx.x  (R8 version, reverted)
// ---------------------------------------------------------------------------
__global__ __launch_bounds__(256) void prep_fused(
    const float* __restrict__ W2,  // [4096,4096]
    const float* __restrict__ W,   // [64,64]
    const float* __restrict__ b2,  // [4096]
    const float* __restrict__ Y,   // [4096,64]
    const float* __restrict__ W1,  // [64,4096]
    const float* __restrict__ b1,  // [4096]
    bf16* __restrict__ W2fT,       // [4096,4096] (n, p)
    float* __restrict__ b2f,       // [4096]
    bf16* __restrict__ h)          // [4096,4096]
{
    __shared__ __align__(16) char smem[45056];
    int t = threadIdx.x, bid = blockIdx.x;
    int w = t >> 6, l = t & 63;
    int lm = l & 15, q2 = l >> 4, q8 = q2 * 8;

    if (bid < 2048) {
        // ---- fold_w2 ----
        int pt = bid & 31, i = bid >> 5;
        bf16* sW = (bf16*)smem;          // 64*72
        bf16* sA = sW + 64 * 72;         // 128*72
        bf16* sT = sA + 128 * 72;        // 64*136
        int p0 = pt * 128;

#pragma unroll
        for (int kk = 0; kk < 4; kk++) {
            int idx4 = t + 256 * kk;           // 1024 float4 total
            float4 v = *(const float4*)(W + (size_t)idx4 * 4);
            int row = (idx4 * 4) >> 6, col = (idx4 * 4) & 63;
            bf16 tmp[4] = {(bf16)v.x, (bf16)v.y, (bf16)v.z, (bf16)v.w};
            *(uint2*)(sW + row * 72 + col) = *(const uint2*)tmp;
        }
        {
            const float* src = W2 + (size_t)p0 * 4096 + i * 64;
#pragma unroll
            for (int kk = 0; kk < 8; kk++) {
                int c = t + 256 * kk;
                int row = c >> 4, j4 = (c & 15) * 4;
                float4 v = *(const float4*)(src + (size_t)row * 4096 + j4);
                bf16 tmp[4] = {(bf16)v.x, (bf16)v.y, (bf16)v.z, (bf16)v.w};
                *(uint2*)(sA + row * 72 + j4) = *(const uint2*)tmp;
            }
        }
        __syncthreads();

        floatx4 acc[2][4] = {};
#pragma unroll
        for (int kc = 0; kc < 2; kc++) {
            bf16x8 a0 = *(const bf16x8*)(sA + (w * 32 + lm) * 72 + kc * 32 + q8);
            bf16x8 a1 = *(const bf16x8*)(sA + (w * 32 + 16 + lm) * 72 + kc * 32 + q8);
#pragma unroll
            for (int jn = 0; jn < 4; jn++) {
                bf16x8 bf_ = *(const bf16x8*)(sW + (jn * 16 + lm) * 72 + kc * 32 + q8);
                acc[0][jn] = MFMA16(a0, bf_, acc[0][jn]);
                acc[1][jn] = MFMA16(a1, bf_, acc[1][jn]);
            }
        }
#pragma unroll
        for (int im = 0; im < 2; im++)
#pragma unroll
            for (int jn = 0; jn < 4; jn++) {
                int pr = w * 32 + im * 16 + q2 * 4;
                int lc = jn * 16 + lm;
                union { bf16 h4[4]; uint2 u; } pk;
#pragma unroll
                for (int r = 0; r < 4; r++) pk.h4[r] = (bf16)acc[im][jn][r];
                *(uint2*)(sT + lc * 136 + pr) = pk.u;
            }
        __syncthreads();
#pragma unroll
        for (int kk = 0; kk < 4; kk++) {
            int c = t + 256 * kk;
            int row = c >> 4, off = (c & 15) * 8;
            uint4 v = *(const uint4*)(sT + row * 136 + off);
            *(uint4*)(W2fT + (size_t)(i * 64 + row) * 4096 + p0 + off) = v;
        }
        return;
    }

    if (bid < 2112) {
        // ---- b2f ----
        int i = bid - 2048;
        if (t < 64) {
            float acc = 0.f;
            const float* b2r = b2 + i * 64;
            const float* wr_ = W + t * 64;
#pragma unroll
            for (int j = 0; j < 64; j++) acc = fmaf(b2r[j], wr_[j], acc);
            b2f[i * 64 + t] = acc;
        }
        return;
    }

    // ---- mlp1 via MFMA: h[m,n] = silu(sum_k Y[m,k] W1[k,n] + b1[n]) ----
    {
        int q = bid - 2112;
        int m0 = (q >> 5) * 128, n0 = (q & 31) * 128;
        bf16* sY = (bf16*)smem;          // 128*72  (Y[m,k])
        bf16* sWT = sY + 128 * 72;       // 128*72  (W1T[n,k])

#pragma unroll
        for (int kk = 0; kk < 8; kk++) {
            int c = t + 256 * kk;
            int row = c >> 4, c4 = (c & 15) * 4;
            float4 v = *(const float4*)(Y + (size_t)(m0 + row) * 64 + c4);
            bf16 tmp[4] = {(bf16)v.x, (bf16)v.y, (bf16)v.z, (bf16)v.w};
            *(uint2*)(sY + row * 72 + c4) = *(const uint2*)tmp;
        }
#pragma unroll
        for (int kk = 0; kk < 8; kk++) {
            int c = t + 256 * kk;
            int k = c >> 5, j4 = (c & 31) * 4;
            float4 v = *(const float4*)(W1 + (size_t)k * 4096 + n0 + j4);
            sWT[(j4 + 0) * 72 + k] = (bf16)v.x;
            sWT[(j4 + 1) * 72 + k] = (bf16)v.y;
            sWT[(j4 + 2) * 72 + k] = (bf16)v.z;
            sWT[(j4 + 3) * 72 + k] = (bf16)v.w;
        }
        __syncthreads();

        int wn = (w & 1) * 64, wm = (w >> 1) * 64;
        floatx4 acc[4][4] = {};
#pragma unroll
        for (int kc = 0; kc < 2; kc++) {
            bf16x8 af[4], bfr[4];
#pragma unroll
            for (int i = 0; i < 4; i++)
                af[i] = *(const bf16x8*)(sWT + (wn + i * 16 + lm) * 72 + kc * 32 + q8);
#pragma unroll
            for (int j = 0; j < 4; j++)
                bfr[j] = *(const bf16x8*)(sY + (wm + j * 16 + lm) * 72 + kc * 32 + q8);
#pragma unroll
            for (int i = 0; i < 4; i++)
#pragma unroll
                for (int j = 0; j < 4; j++)
                    acc[i][j] = MFMA16(af[i], bfr[j], acc[i][j]);
        }
#pragma unroll
        for (int i = 0; i < 4; i++) {
            int nb = n0 + wn + i * 16 + q2 * 4;
            float4 bv = *(const float4*)(b1 + nb);
            float bb[4] = {bv.x, bv.y, bv.z, bv.w};
#pragma unroll
            for (int j = 0; j < 4; j++) {
                int m = m0 + wm + j * 16 + lm;
                union { bf16 h4[4]; uint2 u; } pk;
#pragma unroll
                for (int r = 0; r < 4; r++) {
                    float v = acc[i][j][r] + bb[r];
                    v = v / (1.f + __expf(-v));
                    pk.h4[r] = (bf16)v;
                }
                *(uint2*)(h + (size_t)m * 4096 + nb) = pk.u;
            }
        }
    }
}

// ---------------------------------------------------------------------------
// Kernel 2 (R10): R8 skeleton (BK=64 2-slot dbuf, 1 barrier/iter, XCD 4x8)
// with cross-cluster ds_read pipelining: half1's fragment reads are issued
// DURING half0's MFMA clusters so 3 of 4 clusters run with LDS reads in
// flight (R8 alternated read-phase / MFMA-phase -> pipes ~91% serial).
// Gate ledger (in-order DS retire, lgkm field <= 15):
//   issue 12 (bv0,a00 | a10)          pending 12
//   lgkm(4)  -> bv0+a00 landed        (a10 x4 drain under C0)
//   C0; issue 8 (bv1,a01)             pending <= 12
//   lgkm(8)  -> a10 landed            (bv1+a01 x8 drain under C1)
//   C1; issue 4 (a11)                 pending <= 12
//   lgkm(4)  -> bv1+a01 landed        (a11 x4 drain under C2)
//   C2; lgkm(0) -> a11 landed; C3
// Ring/vmcnt/barrier identical to R8 (verified): stage kt+1 issued at top,
// vmcnt(0)+s_barrier at bottom (drain ~3900 cyc after issue -> free).
// ---------------------------------------------------------------------------
__global__ __launch_bounds__(512, 2) void gemm_bt_bias(
    const bf16* __restrict__ A, const bf16* __restrict__ BT,
    const float* __restrict__ bias, bf16* __restrict__ C,
    int M, int N, int K)
{
    __shared__ __align__(16) char lds[131072];  // 2 slots x (A 32K | B 32K)

    int t = threadIdx.x, w = t >> 6, l = t & 63;
    int lm = l & 15, q2 = l >> 4;
    int wm = w >> 2, wn = w & 3;

    int bid = blockIdx.x;
    int xcd = bid & 7, local = bid >> 3;
    int m0 = ((xcd & 3) * 4 + (local >> 3)) * 256;
    int n0 = ((xcd >> 2) * 8 + (local & 7)) * 256;

    // staging: 4 x 16B chunks per thread per operand per stage (2048 chunks).
    // chunk ch: row = ch>>3, phys pos = ch&7, holds source k-chunk
    // (ch&7) ^ (row&7)  [involutive].
    const bf16 *gA0, *gA1, *gA2, *gA3, *gB0, *gB1, *gB2, *gB3;
    {
        int ch, row, ko;
        ch = t;        row = ch >> 3; ko = ((ch & 7) ^ (row & 7)) * 8;
        gA0 = A + (size_t)(m0 + row) * K + ko; gB0 = BT + (size_t)(n0 + row) * K + ko;
        ch = t + 512;  row = ch >> 3; ko = ((ch & 7) ^ (row & 7)) * 8;
        gA1 = A + (size_t)(m0 + row) * K + ko; gB1 = BT + (size_t)(n0 + row) * K + ko;
        ch = t + 1024; row = ch >> 3; ko = ((ch & 7) ^ (row & 7)) * 8;
        gA2 = A + (size_t)(m0 + row) * K + ko; gB2 = BT + (size_t)(n0 + row) * K + ko;
        ch = t + 1536; row = ch >> 3; ko = ((ch & 7) ^ (row & 7)) * 8;
        gA3 = A + (size_t)(m0 + row) * K + ko; gB3 = BT + (size_t)(n0 + row) * K + ko;
    }
    const int dstb = t * 16;   // lane-consecutive within wave

    auto issue = [&](int slot) {
        char* slab = lds + (slot << 16);
        gload_lds16(gA0, slab + dstb);
        gload_lds16(gA1, slab + 8192 + dstb);
        gload_lds16(gA2, slab + 16384 + dstb);
        gload_lds16(gA3, slab + 24576 + dstb);
        gload_lds16(gB0, slab + 32768 + dstb);
        gload_lds16(gB1, slab + 40960 + dstb);
        gload_lds16(gB2, slab + 49152 + dstb);
        gload_lds16(gB3, slab + 57344 + dstb);
        gA0 += 64; gA1 += 64; gA2 += 64; gA3 += 64;
        gB0 += 64; gB1 += 64; gB2 += 64; gB3 += 64;
    };

    // fragment read bases: row*128 + (q2^(lm&7))*16; K-half1 flips bit 6 (^64)
    const int swz = (q2 ^ (lm & 7)) * 16;
    const int base_a = (wm * 128 + lm) * 128 + swz;
    const int base_b = 32768 + (wn * 64 + lm) * 128 + swz;

    floatx4 acc[8][4] = {};

#define SB __builtin_amdgcn_sched_barrier(0)

    auto body = [&](int kt, bool doIssue) {
        const char* slab = lds + ((kt & 1) << 16);
        bf16x8 bv0[4], a00[4], a10[4], bv1[4], a01[4], a11[4];
        // ---- issue all 12 half0 reads (order pinned) ----
#pragma unroll
        for (int j = 0; j < 4; j++) bv0[j] = *(const bf16x8*)(slab + base_b + j * 2048);
#pragma unroll
        for (int i = 0; i < 4; i++) a00[i] = *(const bf16x8*)(slab + base_a + i * 2048);
        SB;
#pragma unroll
        for (int i = 0; i < 4; i++) a10[i] = *(const bf16x8*)(slab + base_a + (4 + i) * 2048);
        if (doIssue) issue((kt + 1) & 1);    // stage next tile (8 gloads)
        asm volatile("s_waitcnt lgkmcnt(4)" ::: "memory");   // bv0+a00 landed
        SB;
        __builtin_amdgcn_s_setprio(1);
#pragma unroll
        for (int i = 0; i < 4; i++)
#pragma unroll
            for (int j = 0; j < 4; j++) acc[i][j] = MFMA16(bv0[j], a00[i], acc[i][j]);
        __builtin_amdgcn_s_setprio(0);
        SB;
        // ---- issue half1 bv+a0 (8 reads) under C1 ----
#pragma unroll
        for (int j = 0; j < 4; j++) bv1[j] = *(const bf16x8*)(slab + (base_b ^ 64) + j * 2048);
#pragma unroll
        for (int i = 0; i < 4; i++) a01[i] = *(const bf16x8*)(slab + (base_a ^ 64) + i * 2048);
        SB;
        asm volatile("s_waitcnt lgkmcnt(8)" ::: "memory");   // a10 landed
        SB;
        __builtin_amdgcn_s_setprio(1);
#pragma unroll
        for (int i = 0; i < 4; i++)
#pragma unroll
            for (int j = 0; j < 4; j++) acc[4 + i][j] = MFMA16(bv0[j], a10[i], acc[4 + i][j]);
        __builtin_amdgcn_s_setprio(0);
        SB;
        // ---- issue half1 a1 (4 reads) under C2 ----
#pragma unroll
        for (int i = 0; i < 4; i++) a11[i] = *(const bf16x8*)(slab + (base_a ^ 64) + (4 + i) * 2048);
        SB;
        asm volatile("s_waitcnt lgkmcnt(4)" ::: "memory");   // bv1+a01 landed
        SB;
        __builtin_amdgcn_s_setprio(1);
#pragma unroll
        for (int i = 0; i < 4; i++)
#pragma unroll
            for (int j = 0; j < 4; j++) acc[i][j] = MFMA16(bv1[j], a01[i], acc[i][j]);
        __builtin_amdgcn_s_setprio(0);
        SB;
        asm volatile("s_waitcnt lgkmcnt(0)" ::: "memory");   // a11 landed
        SB;
        __builtin_amdgcn_s_setprio(1);
#pragma unroll
        for (int i = 0; i < 4; i++)
#pragma unroll
            for (int j = 0; j < 4; j++) acc[4 + i][j] = MFMA16(bv1[j], a11[i], acc[4 + i][j]);
        __builtin_amdgcn_s_setprio(0);
        SB;
        // ---- bottom sync ----
        if (doIssue) {
            asm volatile("s_waitcnt vmcnt(0)" ::: "memory");  // stage kt+1 landed
            __builtin_amdgcn_s_barrier();                     // ... and visible
            SB;
        }
    };

    issue(0);                                       // prime slot 0
    asm volatile("s_waitcnt vmcnt(0)" ::: "memory");
    __builtin_amdgcn_s_barrier();
    SB;
    const int KT = K >> 6;                          // 64 iters of BK=64
    for (int kt = 0; kt < KT; ++kt) body(kt, kt + 1 < KT);

#undef SB

    // epilogue: bias + packed uint2 stores (acc holds 4 consecutive n @ fixed m)
#pragma unroll
    for (int i = 0; i < 8; i++) {
        int m = m0 + wm * 128 + i * 16 + lm;
#pragma unroll
        for (int j = 0; j < 4; j++) {
            int nb = n0 + wn * 64 + j * 16 + q2 * 4;
            float4 b4 = *(const float4*)(bias + nb);
            float bb[4] = {b4.x, b4.y, b4.z, b4.w};
            union { bf16 h4[4]; uint2 u; } pk;
#pragma unroll
            for (int r = 0; r < 4; r++) pk.h4[r] = (bf16)(acc[i][j][r] + bb[r]);
            *(uint2*)(C + (size_t)m * N + nb) = pk.u;
        }
    }
}

// ---------------------------------------------------------------------------
// Kernel 3: out = F X F^T (X symmetric).  (R8 version, reverted.)
// ---------------------------------------------------------------------------
#define ST 72
__global__ __launch_bounds__(256) void batched_congruence(
    const float* __restrict__ x,   // [B,48,48]
    const bf16* __restrict__ F,    // [B,4096]
    float* __restrict__ out)       // [B,4096]
{
    __shared__ bf16 sX[64 * ST], sF[64 * ST], sT[64 * ST];
    int t = threadIdx.x, w = t >> 6, l = t & 63;
    int b = blockIdx.x;
    int lm = l & 15, q2 = l >> 4, q8 = q2 * 8;
    int r0 = (w >> 1) * 32, c0 = (w & 1) * 32;

    const float4* xb = (const float4*)(x + (size_t)b * 2304);
    float4 v0 = xb[t];
    float4 v1 = xb[t + 256];
    float4 v2 = (t < 64) ? xb[t + 512] : make_float4(0.f, 0.f, 0.f, 0.f);

    {
        const uint4* gf = (const uint4*)(F + (size_t)b * 4096);
#pragma unroll
        for (int kk = 0; kk < 2; kk++) {
            int c = t + 256 * kk;
            *(uint4*)(sF + (c >> 3) * ST + (c & 7) * 8) = gf[c];
        }
    }
    // zero X border + padded-diagonal ones (disjoint from x-fill)
    {
        unsigned* sx32 = (unsigned*)sX;
#pragma unroll
        for (int kk = 0; kk < 4; kk++) {
            int idx = t + 256 * kk;
            if (idx < 384) {
                int r = idx >> 3, d = 24 + (idx & 7);
                sx32[r * 36 + d] = 0u;
            } else if (idx < 896) {
                int k2 = idx - 384;
                int r = 48 + (k2 >> 5), d = k2 & 31;
                unsigned val = 0u;
                if (d == (r >> 1)) val = (r & 1) ? 0x3F800000u : 0x00003F80u;
                sx32[r * 36 + d] = val;
            }
        }
    }
    // x fill: rows 0-47, cols 0-47
    {
        int c = t;
        bf16 p4[4];
        p4[0] = (bf16)v0.x; p4[1] = (bf16)v0.y; p4[2] = (bf16)v0.z; p4[3] = (bf16)v0.w;
        *(uint2*)(sX + (c / 12) * ST + (c % 12) * 4) = *(const uint2*)p4;
        c = t + 256;
        p4[0] = (bf16)v1.x; p4[1] = (bf16)v1.y; p4[2] = (bf16)v1.z; p4[3] = (bf16)v1.w;
        *(uint2*)(sX + (c / 12) * ST + (c % 12) * 4) = *(const uint2*)p4;
        if (t < 64) {
            c = t + 512;
            p4[0] = (bf16)v2.x; p4[1] = (bf16)v2.y; p4[2] = (bf16)v2.z; p4[3] = (bf16)v2.w;
            *(uint2*)(sX + (c / 12) * ST + (c % 12) * 4) = *(const uint2*)p4;
        }
    }
    __syncthreads();

    auto mm = [&](const bf16* PA, const bf16* PB, floatx4 acc[2][2]) {
#pragma unroll
        for (int kc = 0; kc < 2; kc++) {
            bf16x8 a0 = *(const bf16x8*)(PA + (r0 + lm) * ST + kc * 32 + q8);
            bf16x8 a1 = *(const bf16x8*)(PA + (r0 + 16 + lm) * ST + kc * 32 + q8);
            bf16x8 b0 = *(const bf16x8*)(PB + (c0 + lm) * ST + kc * 32 + q8);
            bf16x8 b1 = *(const bf16x8*)(PB + (c0 + 16 + lm) * ST + kc * 32 + q8);
            acc[0][0] = MFMA16(a0, b0, acc[0][0]);
            acc[0][1] = MFMA16(a0, b1, acc[0][1]);
            acc[1][0] = MFMA16(a1, b0, acc[1][0]);
            acc[1][1] = MFMA16(a1, b1, acc[1][1]);
        }
    };

    floatx4 z = {0.f, 0.f, 0.f, 0.f};
    {   // S2: Q = X . F^T; transposed store -> sT = T row-major
        floatx4 acc[2][2] = {{z, z}, {z, z}};
        mm(sX, sF, acc);
#pragma unroll
        for (int i = 0; i < 2; i++)
#pragma unroll
            for (int j = 0; j < 2; j++) {
                int R = r0 + i * 16 + q2 * 4;
                int Cc = c0 + j * 16 + lm;
                union { bf16 h4[4]; uint2 u; } pk;
#pragma unroll
                for (int r = 0; r < 4; r++) pk.h4[r] = (bf16)acc[i][j][r];
                *(uint2*)(sT + Cc * ST + R) = pk.u;
            }
    }
    __syncthreads();
    {   // S3: out = T . F^T; coalesced store via sX-reuse (fp32, 2 halves)
        floatx4 acc[2][2] = {{z, z}, {z, z}};
        mm(sT, sF, acc);
        float* stage = (float*)sX;            // 32 x 64 fp32 = 8 KB (sX dead)
        float* ob = out + (size_t)b * 4096;
        // half 0: rows 0..31 come from waves 0,1 (r0 == 0)
        if (w < 2) {
#pragma unroll
            for (int i = 0; i < 2; i++)
#pragma unroll
                for (int j = 0; j < 2; j++) {
                    int R = r0 + i * 16 + q2 * 4;
                    int Cc = c0 + j * 16 + lm;
#pragma unroll
                    for (int r = 0; r < 4; r++) stage[(R + r) * 64 + Cc] = acc[i][j][r];
                }
        }
        __syncthreads();
#pragma unroll
        for (int kk = 0; kk < 2; kk++) {
            int idx = t + 256 * kk;           // 512 float4 = 2048 floats
            *(float4*)(ob + (size_t)idx * 4) = *(const float4*)(stage + (size_t)idx * 4);
        }
        __syncthreads();
        // half 1: rows 32..63 from waves 2,3 (r0 == 32)
        if (w >= 2) {
#pragma unroll
            for (int i = 0; i < 2; i++)
#pragma unroll
                for (int j = 0; j < 2; j++) {
                    int R = r0 + i * 16 + q2 * 4 - 32;
                    int Cc = c0 + j * 16 + lm;
#pragma unroll
                    for (int r = 0; r < 4; r++) stage[(R + r) * 64 + Cc] = acc[i][j][r];
                }
        }
        __syncthreads();
#pragma unroll
        for (int kk = 0; kk < 2; kk++) {
            int idx = t + 256 * kk;
            *(float4*)(ob + 2048 + (size_t)idx * 4) = *(const float4*)(stage + (size_t)idx * 4);
        }
    }
}

// ---------------------------------------------------------------------------
extern "C" void kernel_launch(void* const* d_in, const int* in_sizes, int n_in,
                              void* d_out, int out_size, void* d_ws, size_t ws_size,
                              hipStream_t stream) {
    const float* x  = (const float*)d_in[0];
    const float* Y  = (const float*)d_in[2];
    const float* W  = (const float*)d_in[3];
    const float* W1 = (const float*)d_in[4];
    const float* b1 = (const float*)d_in[5];
    const float* W2 = (const float*)d_in[6];
    const float* b2 = (const float*)d_in[7];
    float* out = (float*)d_out;

    const size_t NN = (size_t)4096 * 4096;
    bf16* h    = (bf16*)d_ws;
    bf16* W2fT = h + NN;
    bf16* emb  = W2fT + NN;
    float* b2f = (float*)d_out;  // stashed in d_out; consumed by GEMM, then overwritten

    prep_fused<<<3136, 256, 0, stream>>>(W2, W, b2, Y, W1, b1, W2fT, b2f, h);
    gemm_bt_bias<<<256, 512, 0, stream>>>(h, W2fT, b2f, emb, 4096, 4096, 4096);
    batched_congruence<<<4096, 256, 0, stream>>>(x, emb, out);
}